// Round 1
// baseline (263.467 us; speedup 1.0000x reference)
//
#include <hip/hip_runtime.h>

// Problem shape (fixed by setup_inputs): B=2, C=4, D=128, H=192, W=192
#define NB 2
#define NS (128 * 192 * 192)      // spatial voxels per batch = 4718592
#define NTOT (NB * NS)            // 9437184
#define NSQ (NS / 4)              // float4-quads per batch = 1179648
#define EPSF 1e-8f
#define INF_BITS 0x7F800000u

// Geometry: 1536 blocks = 6 blocks/CU = 24 waves/CU (matches waves_per_eu max=6).
#define TPB 256
#define BPB 768                    // blocks per batch
#define BLOCKS (2 * BPB)           // 1536
#define STRIDE (BPB * TPB)         // 196608 quads per sweep
#define ITERS (NSQ / STRIDE)       // exactly 6

// Decomposition: loss = -(R0 + sum_{b,j} s_bj*(P_bj - mn_bj*Q_bj)) / NTOT
//   P_bj = sum z_j*(a_j-lse), Q_bj = sum (a_j-lse), R0 = sum (t==0)*(a_0-lse)
// part layout: 16 floats per block: [0..2]=mn [3..5]=mx [6..8]=P [9..11]=Q [12]=R0

typedef float __attribute__((ext_vector_type(4))) f32x4;
typedef int   __attribute__((ext_vector_type(4))) i32x4;

// R10: cached (non-NT) loads — inputs (226.5 MB) fit in the 256 MiB L3; NT
// forfeited any residual hits for zero benefit. Also 2x-unrolled A/B register
// double-buffer replaces the rotating-copy pipeline: no cx=nx moves, and the
// compiler can wait vmcnt(6) (other buffer still in flight) instead of a full
// vmcnt(0) drain each iteration.
__global__ __launch_bounds__(TPB)
__attribute__((amdgpu_waves_per_eu(2, 6)))
void k_fused(const float* __restrict__ x,
             const int* __restrict__ tgt,
             const float* __restrict__ dist,
             float* __restrict__ part) {
    const int b = (blockIdx.x >= BPB) ? 1 : 0;
    const int bid = blockIdx.x - b * BPB;
    const int q0 = bid * TPB + threadIdx.x;

    const float* xb = x + (size_t)b * 4 * NSQ * 4;   // batch base (floats)
    const int*   tb = tgt + (size_t)b * NSQ * 4;
    const float* db = dist + (size_t)b * NSQ * 4;

    float mn1 = __uint_as_float(INF_BITS), mn2 = mn1, mn3 = mn1;
    float mx1 = 0.f, mx2 = 0.f, mx3 = 0.f;
    float P1 = 0.f, P2 = 0.f, P3 = 0.f;
    float Q1 = 0.f, Q2 = 0.f, Q3 = 0.f;
    float R0 = 0.f;

    // Bit-identical math/order vs R9 (absmax must stay 0.0).
    auto vox = [&](float a0, float a1, float a2, float a3, int tt, float dv) {
        float m = fmaxf(fmaxf(a0, a1), fmaxf(a2, a3));
        float e = __expf(a0 - m) + __expf(a1 - m) + __expf(a2 - m) + __expf(a3 - m);
        float lse = m + __logf(e);
        float z1 = (tt == 1) ? dv : 0.f;
        float z2 = (tt == 2) ? dv : 0.f;
        float z3 = (tt == 3) ? dv : 0.f;
        mn1 = fminf(mn1, z1); mx1 = fmaxf(mx1, z1);
        mn2 = fminf(mn2, z2); mx2 = fmaxf(mx2, z2);
        mn3 = fminf(mn3, z3); mx3 = fmaxf(mx3, z3);
        float l1 = a1 - lse, l2 = a2 - lse, l3 = a3 - lse;
        P1 += z1 * l1; P2 += z2 * l2; P3 += z3 * l3;
        Q1 += l1; Q2 += l2; Q3 += l3;
        R0 += (tt == 0) ? (a0 - lse) : 0.f;
    };

    f32x4 ax0, ax1, ax2, ax3, ad;
    i32x4 at;
    f32x4 bx0, bx1, bx2, bx3, bd;
    i32x4 bt;

    auto load6 = [&](int qi, f32x4& x0, f32x4& x1, f32x4& x2, f32x4& x3,
                     i32x4& t4, f32x4& d4) {
        const size_t q = (size_t)qi;
        x0 = *(const f32x4*)(xb + q * 4);
        x1 = *(const f32x4*)(xb + (q + (size_t)NSQ) * 4);
        x2 = *(const f32x4*)(xb + (q + 2 * (size_t)NSQ) * 4);
        x3 = *(const f32x4*)(xb + (q + 3 * (size_t)NSQ) * 4);
        t4 = *(const i32x4*)(tb + q * 4);
        d4 = *(const f32x4*)(db + q * 4);
    };

    load6(q0, ax0, ax1, ax2, ax3, at, ad);              // iter 0 -> A
    load6(q0 + STRIDE, bx0, bx1, bx2, bx3, bt, bd);     // iter 1 -> B

#pragma unroll 1
    for (int i = 0; i < ITERS; i += 2) {
        // consume A (iter i); B's 6 loads stay in flight -> partial vmcnt wait
        vox(ax0.x, ax1.x, ax2.x, ax3.x, at.x, ad.x);
        vox(ax0.y, ax1.y, ax2.y, ax3.y, at.y, ad.y);
        vox(ax0.z, ax1.z, ax2.z, ax3.z, at.z, ad.z);
        vox(ax0.w, ax1.w, ax2.w, ax3.w, at.w, ad.w);
        if (i + 2 < ITERS)
            load6(q0 + (i + 2) * STRIDE, ax0, ax1, ax2, ax3, at, ad);
        // consume B (iter i+1); A's refill stays in flight
        vox(bx0.x, bx1.x, bx2.x, bx3.x, bt.x, bd.x);
        vox(bx0.y, bx1.y, bx2.y, bx3.y, bt.y, bd.y);
        vox(bx0.z, bx1.z, bx2.z, bx3.z, bt.z, bd.z);
        vox(bx0.w, bx1.w, bx2.w, bx3.w, bt.w, bd.w);
        if (i + 3 < ITERS)
            load6(q0 + (i + 3) * STRIDE, bx0, bx1, bx2, bx3, bt, bd);
    }

    // wave(64) butterfly over the 13 accumulators
    for (int off = 32; off; off >>= 1) {
        mn1 = fminf(mn1, __shfl_down(mn1, off, 64));
        mn2 = fminf(mn2, __shfl_down(mn2, off, 64));
        mn3 = fminf(mn3, __shfl_down(mn3, off, 64));
        mx1 = fmaxf(mx1, __shfl_down(mx1, off, 64));
        mx2 = fmaxf(mx2, __shfl_down(mx2, off, 64));
        mx3 = fmaxf(mx3, __shfl_down(mx3, off, 64));
        P1 += __shfl_down(P1, off, 64);
        P2 += __shfl_down(P2, off, 64);
        P3 += __shfl_down(P3, off, 64);
        Q1 += __shfl_down(Q1, off, 64);
        Q2 += __shfl_down(Q2, off, 64);
        Q3 += __shfl_down(Q3, off, 64);
        R0 += __shfl_down(R0, off, 64);
    }

    __shared__ float sv[4][13];
    const int wid = threadIdx.x >> 6;
    if ((threadIdx.x & 63) == 0) {
        sv[wid][0] = mn1; sv[wid][1] = mn2; sv[wid][2] = mn3;
        sv[wid][3] = mx1; sv[wid][4] = mx2; sv[wid][5] = mx3;
        sv[wid][6] = P1;  sv[wid][7] = P2;  sv[wid][8] = P3;
        sv[wid][9] = Q1;  sv[wid][10] = Q2; sv[wid][11] = Q3;
        sv[wid][12] = R0;
    }
    __syncthreads();
    const int i = threadIdx.x;
    if (i < 13) {
        float v = sv[0][i];
        if (i < 3)      v = fminf(fminf(v, sv[1][i]), fminf(sv[2][i], sv[3][i]));
        else if (i < 6) v = fmaxf(fmaxf(v, sv[1][i]), fmaxf(sv[2][i], sv[3][i]));
        else            v = v + sv[1][i] + sv[2][i] + sv[3][i];
        part[(size_t)blockIdx.x * 16 + i] = v;   // plain store — NO atomics
    }
}

// 512 threads, 1 block: thread t reduces 3 rows of one batch.
// t<256 -> batch 0 rows {lane, lane+256, lane+512}; t>=256 -> batch 1 (+768).
// Waves 0..3 are pure batch-0, waves 4..7 pure batch-1.
__global__ __launch_bounds__(512, 1)
void k_final(const float* __restrict__ part, float* __restrict__ out) {
    const int t = threadIdx.x;
    const int batch = t >> 8;
    const int lane8 = t & 255;

    float mn[3] = {__uint_as_float(INF_BITS), __uint_as_float(INF_BITS), __uint_as_float(INF_BITS)};
    float mx[3] = {0.f, 0.f, 0.f};
    double P[3] = {0, 0, 0}, Q[3] = {0, 0, 0}, R0 = 0;

#pragma unroll
    for (int k = 0; k < 3; k++) {
        const float4* r = (const float4*)(part + (size_t)(batch * BPB + k * 256 + lane8) * 16);
        float4 r0 = r[0];  // mn1 mn2 mn3 mx1
        float4 r1 = r[1];  // mx2 mx3 P1  P2
        float4 r2 = r[2];  // P3  Q1  Q2  Q3
        float4 r3 = r[3];  // R0  -   -   -
        mn[0] = fminf(mn[0], r0.x); mn[1] = fminf(mn[1], r0.y); mn[2] = fminf(mn[2], r0.z);
        mx[0] = fmaxf(mx[0], r0.w); mx[1] = fmaxf(mx[1], r1.x); mx[2] = fmaxf(mx[2], r1.y);
        P[0] += (double)r1.z; P[1] += (double)r1.w; P[2] += (double)r2.x;
        Q[0] += (double)r2.y; Q[1] += (double)r2.z; Q[2] += (double)r2.w;
        R0 += (double)r3.x;
    }

    for (int off = 32; off; off >>= 1) {
#pragma unroll
        for (int j = 0; j < 3; j++) {
            mn[j] = fminf(mn[j], __shfl_down(mn[j], off, 64));
            mx[j] = fmaxf(mx[j], __shfl_down(mx[j], off, 64));
            P[j] += __shfl_down(P[j], off, 64);
            Q[j] += __shfl_down(Q[j], off, 64);
        }
        R0 += __shfl_down(R0, off, 64);
    }

    __shared__ float smn[8][3], smx[8][3];
    __shared__ double sP[8][3], sQ[8][3], sR[8];
    const int wid = t >> 6;   // waves 0..3 = batch 0, waves 4..7 = batch 1
    if ((t & 63) == 0) {
#pragma unroll
        for (int j = 0; j < 3; j++) {
            smn[wid][j] = mn[j]; smx[wid][j] = mx[j];
            sP[wid][j] = P[j];   sQ[wid][j] = Q[j];
        }
        sR[wid] = R0;
    }
    __syncthreads();
    if (t == 0) {
        double acc = 0.0;
#pragma unroll
        for (int b = 0; b < 2; b++) {
            double Pb[3] = {0, 0, 0}, Qb[3] = {0, 0, 0};
            float mnb[3], mxb[3];
#pragma unroll
            for (int j = 0; j < 3; j++) { mnb[j] = __uint_as_float(INF_BITS); mxb[j] = 0.f; }
#pragma unroll
            for (int w = 4 * b; w < 4 * b + 4; w++) {
                acc += sR[w];
#pragma unroll
                for (int j = 0; j < 3; j++) {
                    mnb[j] = fminf(mnb[j], smn[w][j]);
                    mxb[j] = fmaxf(mxb[j], smx[w][j]);
                    Pb[j] += sP[w][j];
                    Qb[j] += sQ[w][j];
                }
            }
#pragma unroll
            for (int j = 0; j < 3; j++) {
                float sf = 1.0f / (mxb[j] + EPSF - mnb[j]);   // mirror reference fp32 scale
                acc += (double)sf * (Pb[j] - (double)mnb[j] * Qb[j]);
            }
        }
        out[0] = (float)(-acc / (double)NTOT);
    }
}

extern "C" void kernel_launch(void* const* d_in, const int* in_sizes, int n_in,
                              void* d_out, int out_size, void* d_ws, size_t ws_size,
                              hipStream_t stream) {
    const float* net = (const float*)d_in[0];   // [B, C, D, H, W] fp32
    const int* tgt = (const int*)d_in[1];       // [B, 1, D, H, W] int
    const float* dist = (const float*)d_in[2];  // [B, D, H, W] fp32
    float* part = (float*)d_ws;                 // 1536 x 16 floats = 98 KB

    k_fused<<<BLOCKS, TPB, 0, stream>>>(net, tgt, dist, part);
    k_final<<<1, 512, 0, stream>>>(part, (float*)d_out);
}